// Round 2
// 990.751 us; speedup vs baseline: 1.0019x; 1.0019x over previous
//
#include <hip/hip_runtime.h>
#include <stdint.h>

// LocallyGroupedSelfAttention (B=512,N=200,C=512,NH=8,WS=5,HD=64).
// Dtype-robust: a sniff kernel detects fp32 vs packed-bf16 inputs at runtime;
// all math runs in bf16 MFMA either way; output written fp32 or bf16 per flag.
// Pipeline: sniff -> prep bias/weights(T) -> 4x [conv_x, qkv GEMM, window attn]
// -> proj GEMM. ws ~212 MB.
// R1: GEMM staging switched from sync register-staging to async
// global_load_lds dwordx4 (m97 structure) — everything else unchanged.
// R2: identical resubmit (R1 bench failed on GPU acquisition, no data).

typedef unsigned short u16;
typedef __bf16 bf16_t;
typedef bf16_t bf16x8 __attribute__((ext_vector_type(8)));
typedef float f32x4 __attribute__((ext_vector_type(4)));
typedef u16 u16x8 __attribute__((ext_vector_type(8)));

__device__ __forceinline__ float b2f(u16 u) {
  return __uint_as_float(((uint32_t)u) << 16);
}
__device__ __forceinline__ u16 f2b(float f) {
  uint32_t u = __float_as_uint(f);
  u += 0x7FFFu + ((u >> 16) & 1u);  // RNE
  return (u16)(u >> 16);
}

// async global -> LDS, 16 B per lane; LDS dest is wave-uniform base + lane*16.
#define GLOAD_LDS16(g, l)                                     \
  __builtin_amdgcn_global_load_lds(                           \
      (const __attribute__((address_space(1))) void*)(g),     \
      (__attribute__((address_space(3))) void*)(l), 16, 0, 0)

// flag = 1 if x looks like fp32, 0 if packed bf16 pairs.
__global__ void k_sniff(const uint32_t* __restrict__ x,
                        uint32_t* __restrict__ flag) {
  if (threadIdx.x == 0 && blockIdx.x == 0) {
    int cnt = 0;
    for (int i = 0; i < 256; ++i) {
      uint32_t e = (x[i] >> 23) & 0xFFu;
      if (e >= 64u && e <= 192u) ++cnt;  // fp32 N(0,1) exponents land here
    }
    *flag = (cnt >= 128) ? 1u : 0u;
  }
}

__global__ void k_prep_bias(const void* __restrict__ qb,
                            const void* __restrict__ pb,
                            const uint32_t* __restrict__ flag,
                            u16* __restrict__ bq, u16* __restrict__ bp) {
  const bool f = (*flag) != 0;
  int i = blockIdx.x * 256 + threadIdx.x;
  if (i < 1536)
    bq[i] = f ? f2b(((const float*)qb)[i]) : ((const u16*)qb)[i];
  else {
    int j = i - 1536;
    if (j < 512) bp[j] = f ? f2b(((const float*)pb)[j]) : ((const u16*)pb)[j];
  }
}

// in[R][Cc] (fp32 or bf16 per flag) -> out[Cc][R] bf16. block (32,8).
__global__ void k_prep_w(const void* __restrict__ in, u16* __restrict__ out,
                         const uint32_t* __restrict__ flag, int R, int Cc) {
  __shared__ u16 tile[32][33];
  const bool f = (*flag) != 0;
  const int bx = blockIdx.x * 32, by = blockIdx.y * 32;
  const int tx = threadIdx.x, ty = threadIdx.y;
  for (int i = ty; i < 32; i += 8) {
    size_t idx = (size_t)(by + i) * Cc + bx + tx;
    tile[i][tx] = f ? f2b(((const float*)in)[idx]) : ((const u16*)in)[idx];
  }
  __syncthreads();
  for (int i = ty; i < 32; i += 8)
    out[(size_t)(bx + i) * R + by + tx] = tile[tx][i];
}

// fp32 -> bf16 chunk convert (no-op when inputs already bf16)
__global__ void k_conv_x(const float* __restrict__ x, u16* __restrict__ xb,
                         const uint32_t* __restrict__ flag, int n) {
  if ((*flag) == 0) return;
  int i = (blockIdx.x * 256 + threadIdx.x) * 8;
  if (i >= n) return;
  float4 a = *(const float4*)&x[i];
  float4 b = *(const float4*)&x[i + 4];
  u16x8 o;
  o[0] = f2b(a.x); o[1] = f2b(a.y); o[2] = f2b(a.z); o[3] = f2b(a.w);
  o[4] = f2b(b.x); o[5] = f2b(b.y); o[6] = f2b(b.z); o[7] = f2b(b.w);
  *(u16x8*)&xb[i] = o;
}

// ------------------------------------------------------------------- GEMM
// C[M][N] = A[M][K] @ Bt[N][K]^T + bias. 128x128 tile, BK=32, 4 waves 2x2.
// m97 structure: async global_load_lds dwordx4 staging, single LDS buffer,
// 2 barriers per K-step (compiler inserts the vmcnt drain at the first).
#define BM 128
#define BN 128
#define BK 32

__global__ __launch_bounds__(256) void gemm_bt_bias(
    const u16* __restrict__ A0,  // A when flag==0 (bf16 world)
    const u16* __restrict__ A1,  // A when flag==1 (pre-converted bf16)
    const u16* __restrict__ Bt, const u16* __restrict__ bias,
    void* __restrict__ Cout, const uint32_t* __restrict__ flag,
    int N, int K, int out_f32_if_flag) {
  __shared__ u16 smem[BM * BN];  // 32 KB; staging in first 16 KB
  u16* As = smem;                // [BM][BK] row-major (64 B rows)
  u16* Bs = smem + BM * BK;      // [BN][BK]

  const bool f = (*flag) != 0;
  const u16* A = f ? A1 : A0;

  const int t = threadIdx.x;
  const int wave = t >> 6;
  const int lane = t & 63;
  const int waveM = wave & 1;
  const int waveN = wave >> 1;
  const int bm = blockIdx.y * BM;
  const int bn = blockIdx.x * BN;

  const int kq = (lane >> 4) * 8;
  const int l15 = lane & 15;

  // Staging geometry: one gload_lds = 64 lanes x 16 B = 1024 B = 16 LDS rows.
  // Chunk j covers rows [j*16, j*16+16); lane covers row j*16 + (lane>>2),
  // cols (lane&3)*8 .. +8 (u16). Wave w owns chunks {2w, 2w+1} of A and B.
  const int srow = lane >> 2;
  const int scol = (lane & 3) * 8;
  const int j0 = wave * 2;

  const u16* Ag0 = &A[(size_t)(bm + j0 * 16 + srow) * K + scol];
  const u16* Ag1 = &A[(size_t)(bm + (j0 + 1) * 16 + srow) * K + scol];
  const u16* Bg0 = &Bt[(size_t)(bn + j0 * 16 + srow) * K + scol];
  const u16* Bg1 = &Bt[(size_t)(bn + (j0 + 1) * 16 + srow) * K + scol];
  u16* Al0 = &As[j0 * 512];        // wave-uniform LDS bases (512 u16 = 1 KiB)
  u16* Al1 = &As[(j0 + 1) * 512];
  u16* Bl0 = &Bs[j0 * 512];
  u16* Bl1 = &Bs[(j0 + 1) * 512];

  f32x4 acc[4][4] = {};

  for (int k0 = 0; k0 < K; k0 += BK) {
    GLOAD_LDS16(Ag0 + k0, Al0);
    GLOAD_LDS16(Ag1 + k0, Al1);
    GLOAD_LDS16(Bg0 + k0, Bl0);
    GLOAD_LDS16(Bg1 + k0, Bl1);
    __syncthreads();  // vmcnt drain + barrier: tile resident in LDS

    bf16x8 af[4], bfr[4];
#pragma unroll
    for (int i = 0; i < 4; ++i)
      af[i] = *(const bf16x8*)&As[(waveM * 64 + i * 16 + l15) * BK + kq];
#pragma unroll
    for (int j = 0; j < 4; ++j)
      bfr[j] = *(const bf16x8*)&Bs[(waveN * 64 + j * 16 + l15) * BK + kq];
#pragma unroll
    for (int i = 0; i < 4; ++i)
#pragma unroll
      for (int j = 0; j < 4; ++j)
        acc[i][j] = __builtin_amdgcn_mfma_f32_16x16x32_bf16(af[i], bfr[j],
                                                            acc[i][j], 0, 0, 0);
    __syncthreads();  // all waves done reading before next stage overwrites
  }

  float biasf[4];
#pragma unroll
  for (int j = 0; j < 4; ++j)
    biasf[j] = b2f(bias[bn + waveN * 64 + j * 16 + l15]);

  // C/D frag: col = lane&15, row = (lane>>4)*4 + reg  [m89/m91]
  if (out_f32_if_flag && f) {
    float* C = (float*)Cout;
#pragma unroll
    for (int i = 0; i < 4; ++i) {
      const int row0 = waveM * 64 + i * 16 + (lane >> 4) * 4;
#pragma unroll
      for (int j = 0; j < 4; ++j) {
        const int col = waveN * 64 + j * 16 + l15;
#pragma unroll
        for (int r = 0; r < 4; ++r)
          C[(size_t)(bm + row0 + r) * N + bn + col] = acc[i][j][r] + biasf[j];
      }
    }
  } else {
    u16* C = (u16*)Cout;
    __syncthreads();  // staging area now reusable for repack
#pragma unroll
    for (int i = 0; i < 4; ++i) {
      const int row0 = waveM * 64 + i * 16 + (lane >> 4) * 4;
#pragma unroll
      for (int j = 0; j < 4; ++j) {
        const int col = waveN * 64 + j * 16 + l15;
#pragma unroll
        for (int r = 0; r < 4; ++r)
          smem[(row0 + r) * BN + col] = f2b(acc[i][j][r] + biasf[j]);
      }
    }
    __syncthreads();
#pragma unroll
    for (int s = 0; s < 8; ++s) {
      const int vi = s * 256 + t;
      const int row = vi >> 4;
      const int col = (vi & 15) * 8;
      u16x8 v = *(const u16x8*)&smem[row * BN + col];
      *(u16x8*)&C[(size_t)(bm + row) * N + bn + col] = v;
    }
  }
}

// ------------------------------------------------------------- attention
// qkv[rows][1536]: Q [0,512), K [512,1024), V [1024,1536); head h at h*64.
// One wave per (window,head); lane = head dim.
__global__ __launch_bounds__(256) void attn_win(const u16* __restrict__ qkv,
                                                u16* __restrict__ o,
                                                int nwin) {
  const int wid = blockIdx.x * 4 + (threadIdx.x >> 6);
  const int lane = threadIdx.x & 63;
  const int h = wid & 7;
  const int w = wid >> 3;
  if (w >= nwin) return;
  const u16* base = qkv + (size_t)w * (5 * 1536) + h * 64 + lane;

  float q[5], k[5], v[5];
#pragma unroll
  for (int i = 0; i < 5; ++i) {
    q[i] = b2f(base[i * 1536]);
    k[i] = b2f(base[i * 1536 + 512]);
    v[i] = b2f(base[i * 1536 + 1024]);
  }
  float s[5][5];
#pragma unroll
  for (int i = 0; i < 5; ++i)
#pragma unroll
    for (int j = 0; j < 5; ++j) s[i][j] = q[i] * k[j];
#pragma unroll
  for (int off = 32; off > 0; off >>= 1) {
#pragma unroll
    for (int i = 0; i < 5; ++i)
#pragma unroll
      for (int j = 0; j < 5; ++j) s[i][j] += __shfl_xor(s[i][j], off, 64);
  }
  const float SCALE = 0.125f;  // 64^-0.5
  u16* ob = o + (size_t)w * (5 * 512) + h * 64 + lane;
#pragma unroll
  for (int i = 0; i < 5; ++i) {
    float m = s[i][0];
#pragma unroll
    for (int j = 1; j < 5; ++j) m = fmaxf(m, s[i][j]);
    float l = 0.f, acc = 0.f;
#pragma unroll
    for (int j = 0; j < 5; ++j) {
      float e = __expf((s[i][j] - m) * SCALE);
      l += e;
      acc += e * v[j];
    }
    ob[i * 512] = f2b(acc / l);
  }
}

// ---------------------------------------------------------------- launch
extern "C" void kernel_launch(void* const* d_in, const int* in_sizes, int n_in,
                              void* d_out, int out_size, void* d_ws,
                              size_t ws_size, hipStream_t stream) {
  const void* x      = d_in[0];  // [102400][512]  fp32 or bf16
  const void* qkv_w  = d_in[1];  // [512][1536]
  const void* qkv_b  = d_in[2];  // [1536]
  const void* proj_w = d_in[3];  // [512][512]
  const void* proj_b = d_in[4];  // [512]

  const int M = 102400, K = 512, N1 = 1536, N2 = 512;
  const int CH = 4, MC = M / CH;  // 25600 rows/chunk

  char* ws = (char*)d_ws;
  uint32_t* flag = (uint32_t*)ws;                       // @0
  u16* bq      = (u16*)(ws + 256);                      // 1536*2
  u16* bp      = (u16*)(ws + 256 + 3072);               // 512*2
  u16* wt_qkv  = (u16*)(ws + 8192);                     // 1536*512*2
  u16* wt_proj = (u16*)(ws + 8192 + 1572864);           // 512*512*2
  u16* attnb   = (u16*)(ws + 8192 + 1572864 + 524288);  // M*512*2 = 104.9 MB
  u16* qkvc    = (u16*)((char*)attnb + (size_t)M * 512 * 2);   // MC*1536*2
  u16* xbc     = (u16*)((char*)qkvc + (size_t)MC * 1536 * 2);  // MC*512*2
  // total ~212 MB

  k_sniff<<<1, 64, 0, stream>>>((const uint32_t*)x, flag);
  k_prep_bias<<<8, 256, 0, stream>>>(qkv_b, proj_b, flag, bq, bp);
  k_prep_w<<<dim3(N1 / 32, K / 32), dim3(32, 8), 0, stream>>>(qkv_w, wt_qkv,
                                                              flag, K, N1);
  k_prep_w<<<dim3(N2 / 32, K / 32), dim3(32, 8), 0, stream>>>(proj_w, wt_proj,
                                                              flag, K, N2);
  for (int c = 0; c < CH; ++c) {
    const size_t roff = (size_t)c * MC * 512;
    k_conv_x<<<MC * 512 / 2048, 256, 0, stream>>>((const float*)x + roff, xbc,
                                                  flag, MC * 512);
    gemm_bt_bias<<<dim3(N1 / BN, MC / BM), 256, 0, stream>>>(
        (const u16*)x + roff, xbc, wt_qkv, bq, qkvc, flag, N1, K, 0);
    attn_win<<<(MC / 5) * 8 / 4, 256, 0, stream>>>(qkvc, (u16*)attnb + roff,
                                                   MC / 5);
  }
  gemm_bt_bias<<<dim3(N2 / BN, M / BM), 256, 0, stream>>>(
      attnb, attnb, wt_proj, bp, d_out, flag, N2, K, 1);
}

// Round 3
// 968.145 us; speedup vs baseline: 1.0253x; 1.0233x over previous
//
#include <hip/hip_runtime.h>
#include <stdint.h>

// LocallyGroupedSelfAttention (B=512,N=200,C=512,NH=8,WS=5,HD=64).
// Dtype-robust: a sniff kernel detects fp32 vs packed-bf16 inputs at runtime;
// all math runs in bf16 MFMA either way; output written fp32 or bf16 per flag.
// Pipeline: sniff -> prep bias/weights(T) -> 4x [conv_x, qkv GEMM, window attn]
// -> proj GEMM. ws ~212 MB.
// R1: global_load_lds staging (m97) — marginal; K=512 is latency-bound.
// R3: 256x256 tile, 8 waves, 2-phase double-buffered LDS (stage t+1 before
// compute t, one barrier/step) + bijective XCD swizzle on the GEMM grid.

typedef unsigned short u16;
typedef __bf16 bf16_t;
typedef bf16_t bf16x8 __attribute__((ext_vector_type(8)));
typedef float f32x4 __attribute__((ext_vector_type(4)));
typedef u16 u16x8 __attribute__((ext_vector_type(8)));

__device__ __forceinline__ float b2f(u16 u) {
  return __uint_as_float(((uint32_t)u) << 16);
}
__device__ __forceinline__ u16 f2b(float f) {
  uint32_t u = __float_as_uint(f);
  u += 0x7FFFu + ((u >> 16) & 1u);  // RNE
  return (u16)(u >> 16);
}

// async global -> LDS, 16 B per lane; LDS dest is wave-uniform base + lane*16.
#define GLOAD_LDS16(g, l)                                     \
  __builtin_amdgcn_global_load_lds(                           \
      (const __attribute__((address_space(1))) void*)(g),     \
      (__attribute__((address_space(3))) void*)(l), 16, 0, 0)

// flag = 1 if x looks like fp32, 0 if packed bf16 pairs.
__global__ void k_sniff(const uint32_t* __restrict__ x,
                        uint32_t* __restrict__ flag) {
  if (threadIdx.x == 0 && blockIdx.x == 0) {
    int cnt = 0;
    for (int i = 0; i < 256; ++i) {
      uint32_t e = (x[i] >> 23) & 0xFFu;
      if (e >= 64u && e <= 192u) ++cnt;  // fp32 N(0,1) exponents land here
    }
    *flag = (cnt >= 128) ? 1u : 0u;
  }
}

__global__ void k_prep_bias(const void* __restrict__ qb,
                            const void* __restrict__ pb,
                            const uint32_t* __restrict__ flag,
                            u16* __restrict__ bq, u16* __restrict__ bp) {
  const bool f = (*flag) != 0;
  int i = blockIdx.x * 256 + threadIdx.x;
  if (i < 1536)
    bq[i] = f ? f2b(((const float*)qb)[i]) : ((const u16*)qb)[i];
  else {
    int j = i - 1536;
    if (j < 512) bp[j] = f ? f2b(((const float*)pb)[j]) : ((const u16*)pb)[j];
  }
}

// in[R][Cc] (fp32 or bf16 per flag) -> out[Cc][R] bf16. block (32,8).
__global__ void k_prep_w(const void* __restrict__ in, u16* __restrict__ out,
                         const uint32_t* __restrict__ flag, int R, int Cc) {
  __shared__ u16 tile[32][33];
  const bool f = (*flag) != 0;
  const int bx = blockIdx.x * 32, by = blockIdx.y * 32;
  const int tx = threadIdx.x, ty = threadIdx.y;
  for (int i = ty; i < 32; i += 8) {
    size_t idx = (size_t)(by + i) * Cc + bx + tx;
    tile[i][tx] = f ? f2b(((const float*)in)[idx]) : ((const u16*)in)[idx];
  }
  __syncthreads();
  for (int i = ty; i < 32; i += 8)
    out[(size_t)(bx + i) * R + by + tx] = tile[tx][i];
}

// fp32 -> bf16 chunk convert (no-op when inputs already bf16)
__global__ void k_conv_x(const float* __restrict__ x, u16* __restrict__ xb,
                         const uint32_t* __restrict__ flag, int n) {
  if ((*flag) == 0) return;
  int i = (blockIdx.x * 256 + threadIdx.x) * 8;
  if (i >= n) return;
  float4 a = *(const float4*)&x[i];
  float4 b = *(const float4*)&x[i + 4];
  u16x8 o;
  o[0] = f2b(a.x); o[1] = f2b(a.y); o[2] = f2b(a.z); o[3] = f2b(a.w);
  o[4] = f2b(b.x); o[5] = f2b(b.y); o[6] = f2b(b.z); o[7] = f2b(b.w);
  *(u16x8*)&xb[i] = o;
}

// ------------------------------------------------------------------- GEMM
// C[M][N] = A[M][K] @ Bt[N][K]^T + bias. 256x256 tile, BK=32, 8 waves 2Mx4N,
// per-wave output 128x64 (8x4 16x16x32 frags). Double-buffered LDS:
// stage step t+1 (4 global_load_lds/wave) BEFORE computing step t; single
// __syncthreads per step drains vmcnt late (load latency hidden by 32 MFMA).
// LDS 64 KB: [buf][A 256x32 | B 256x32] u16, linear rows (64 B) for gload_lds.
#define BM 256
#define BN 256
#define BK 32

__global__ __launch_bounds__(512, 2) void gemm_bt_bias(
    const u16* __restrict__ A0,  // A when flag==0 (bf16 world)
    const u16* __restrict__ A1,  // A when flag==1 (pre-converted bf16)
    const u16* __restrict__ Bt, const u16* __restrict__ bias,
    void* __restrict__ Cout, const uint32_t* __restrict__ flag,
    int N, int K, int out_f32_if_flag) {
  __shared__ u16 smem[32768];  // 64 KB: As0@0, Bs0@8192, As1@16384, Bs1@24576

  const bool f = (*flag) != 0;
  const u16* A = f ? A1 : A0;

  const int t = threadIdx.x;
  const int wave = t >> 6;         // 0..7
  const int lane = t & 63;
  const int waveM = wave >> 2;     // 0..1  -> M offset waveM*128
  const int waveN = wave & 3;      // 0..3  -> N offset waveN*64

  // T1: bijective XCD swizzle (grid sizes are multiples of 8 by construction)
  const int nbx = gridDim.x;
  const int nwg = nbx * gridDim.y;
  const int bid = blockIdx.y * nbx + blockIdx.x;
  const int cpx = nwg >> 3;
  const int swz = (bid & 7) * cpx + (bid >> 3);
  const int bm = (swz / nbx) * BM;
  const int bn = (swz % nbx) * BN;

  const int kq = (lane >> 4) * 8;  // K sub-offset for MFMA frag
  const int l15 = lane & 15;

  // Staging: one gload_lds = 64 lanes x 16 B = 1 KiB = 16 LDS rows of [*][32].
  // Chunk j covers rows [j*16, j*16+16); lane -> row j*16+(lane>>2),
  // u16 col (lane&3)*8. Wave w owns chunks {2w, 2w+1} of A and of B.
  const int srow = lane >> 2;
  const int scol = (lane & 3) * 8;
  const int j0 = wave * 2;

  const u16* Agp = &A[(size_t)(bm + j0 * 16 + srow) * K + scol];
  const u16* Bgp = &Bt[(size_t)(bn + j0 * 16 + srow) * K + scol];

#define STAGE(b, k0)                                              \
  {                                                               \
    u16* as_ = smem + (b) * 16384 + j0 * 512;                     \
    u16* bs_ = smem + (b) * 16384 + 8192 + j0 * 512;              \
    GLOAD_LDS16(Agp + (size_t)(k0), as_);                         \
    GLOAD_LDS16(Agp + (size_t)(k0) + 16 * (size_t)K, as_ + 512);  \
    GLOAD_LDS16(Bgp + (size_t)(k0), bs_);                         \
    GLOAD_LDS16(Bgp + (size_t)(k0) + 16 * (size_t)K, bs_ + 512);  \
  }

  f32x4 acc[8][4] = {};

#define COMPUTE(b)                                                        \
  {                                                                       \
    const u16* As_ = smem + (b) * 16384;                                  \
    const u16* Bs_ = As_ + 8192;                                          \
    bf16x8 af[8], bfr[4];                                                 \
    _Pragma("unroll") for (int i = 0; i < 8; ++i)                         \
        af[i] = *(const bf16x8*)&As_[(waveM * 128 + i * 16 + l15) * BK + kq]; \
    _Pragma("unroll") for (int j = 0; j < 4; ++j)                         \
        bfr[j] = *(const bf16x8*)&Bs_[(waveN * 64 + j * 16 + l15) * BK + kq]; \
    _Pragma("unroll") for (int i = 0; i < 8; ++i)                         \
        _Pragma("unroll") for (int j = 0; j < 4; ++j)                     \
            acc[i][j] = __builtin_amdgcn_mfma_f32_16x16x32_bf16(          \
                af[i], bfr[j], acc[i][j], 0, 0, 0);                       \
  }

  const int NSTEP = K / BK;  // 16 (even)
  STAGE(0, 0);
  __syncthreads();  // drain: buf0 resident
  for (int s = 0; s + 2 < NSTEP; s += 2) {
    STAGE(1, (s + 1) * BK);   // issue next while computing current
    COMPUTE(0);
    __syncthreads();          // late drain: buf1 ready, buf0 reads done
    STAGE(0, (s + 2) * BK);
    COMPUTE(1);
    __syncthreads();
  }
  STAGE(1, (NSTEP - 1) * BK);
  COMPUTE(0);
  __syncthreads();
  COMPUTE(1);
  __syncthreads();  // LDS now reusable for epilogue repack

  float biasf[4];
#pragma unroll
  for (int j = 0; j < 4; ++j)
    biasf[j] = b2f(bias[bn + waveN * 64 + j * 16 + l15]);

  // C/D frag: col = lane&15, row = (lane>>4)*4 + reg  [m89/m91]
  if (out_f32_if_flag && f) {
    float* C = (float*)Cout;
#pragma unroll
    for (int i = 0; i < 8; ++i) {
      const int row0 = waveM * 128 + i * 16 + (lane >> 4) * 4;
#pragma unroll
      for (int j = 0; j < 4; ++j) {
        const int col = waveN * 64 + j * 16 + l15;
#pragma unroll
        for (int r = 0; r < 4; ++r)
          C[(size_t)(bm + row0 + r) * N + bn + col] = acc[i][j][r] + biasf[j];
      }
    }
  } else {
    // bf16 out: repack 128 rows at a time through LDS (64 KB = 128x256 u16)
    u16* C = (u16*)Cout;
#pragma unroll
    for (int h = 0; h < 2; ++h) {
      if (waveM == h) {
#pragma unroll
        for (int i = 0; i < 8; ++i) {
          const int row0 = i * 16 + (lane >> 4) * 4;  // 0..127
#pragma unroll
          for (int j = 0; j < 4; ++j) {
            const int col = waveN * 64 + j * 16 + l15;
#pragma unroll
            for (int r = 0; r < 4; ++r)
              smem[(row0 + r) * 256 + col] = f2b(acc[i][j][r] + biasf[j]);
          }
        }
      }
      __syncthreads();
#pragma unroll
      for (int s = 0; s < 8; ++s) {
        const int vi = s * 512 + t;
        const int row = vi >> 5;           // 0..127
        const int col = (vi & 31) * 8;     // 0..248
        u16x8 v = *(const u16x8*)&smem[row * 256 + col];
        *(u16x8*)&C[(size_t)(bm + h * 128 + row) * N + bn + col] = v;
      }
      __syncthreads();
    }
  }
#undef STAGE
#undef COMPUTE
}

// ------------------------------------------------------------- attention
// qkv[rows][1536]: Q [0,512), K [512,1024), V [1024,1536); head h at h*64.
// One wave per (window,head); lane = head dim.
__global__ __launch_bounds__(256) void attn_win(const u16* __restrict__ qkv,
                                                u16* __restrict__ o,
                                                int nwin) {
  const int wid = blockIdx.x * 4 + (threadIdx.x >> 6);
  const int lane = threadIdx.x & 63;
  const int h = wid & 7;
  const int w = wid >> 3;
  if (w >= nwin) return;
  const u16* base = qkv + (size_t)w * (5 * 1536) + h * 64 + lane;

  float q[5], k[5], v[5];
#pragma unroll
  for (int i = 0; i < 5; ++i) {
    q[i] = b2f(base[i * 1536]);
    k[i] = b2f(base[i * 1536 + 512]);
    v[i] = b2f(base[i * 1536 + 1024]);
  }
  float s[5][5];
#pragma unroll
  for (int i = 0; i < 5; ++i)
#pragma unroll
    for (int j = 0; j < 5; ++j) s[i][j] = q[i] * k[j];
#pragma unroll
  for (int off = 32; off > 0; off >>= 1) {
#pragma unroll
    for (int i = 0; i < 5; ++i)
#pragma unroll
      for (int j = 0; j < 5; ++j) s[i][j] += __shfl_xor(s[i][j], off, 64);
  }
  const float SCALE = 0.125f;  // 64^-0.5
  u16* ob = o + (size_t)w * (5 * 512) + h * 64 + lane;
#pragma unroll
  for (int i = 0; i < 5; ++i) {
    float m = s[i][0];
#pragma unroll
    for (int j = 1; j < 5; ++j) m = fmaxf(m, s[i][j]);
    float l = 0.f, acc = 0.f;
#pragma unroll
    for (int j = 0; j < 5; ++j) {
      float e = __expf((s[i][j] - m) * SCALE);
      l += e;
      acc += e * v[j];
    }
    ob[i * 512] = f2b(acc / l);
  }
}

// ---------------------------------------------------------------- launch
extern "C" void kernel_launch(void* const* d_in, const int* in_sizes, int n_in,
                              void* d_out, int out_size, void* d_ws,
                              size_t ws_size, hipStream_t stream) {
  const void* x      = d_in[0];  // [102400][512]  fp32 or bf16
  const void* qkv_w  = d_in[1];  // [512][1536]
  const void* qkv_b  = d_in[2];  // [1536]
  const void* proj_w = d_in[3];  // [512][512]
  const void* proj_b = d_in[4];  // [512]

  const int M = 102400, K = 512, N1 = 1536, N2 = 512;
  const int CH = 4, MC = M / CH;  // 25600 rows/chunk

  char* ws = (char*)d_ws;
  uint32_t* flag = (uint32_t*)ws;                       // @0
  u16* bq      = (u16*)(ws + 256);                      // 1536*2
  u16* bp      = (u16*)(ws + 256 + 3072);               // 512*2
  u16* wt_qkv  = (u16*)(ws + 8192);                     // 1536*512*2
  u16* wt_proj = (u16*)(ws + 8192 + 1572864);           // 512*512*2
  u16* attnb   = (u16*)(ws + 8192 + 1572864 + 524288);  // M*512*2 = 104.9 MB
  u16* qkvc    = (u16*)((char*)attnb + (size_t)M * 512 * 2);   // MC*1536*2
  u16* xbc     = (u16*)((char*)qkvc + (size_t)MC * 1536 * 2);  // MC*512*2
  // total ~212 MB

  k_sniff<<<1, 64, 0, stream>>>((const uint32_t*)x, flag);
  k_prep_bias<<<8, 256, 0, stream>>>(qkv_b, proj_b, flag, bq, bp);
  k_prep_w<<<dim3(N1 / 32, K / 32), dim3(32, 8), 0, stream>>>(qkv_w, wt_qkv,
                                                              flag, K, N1);
  k_prep_w<<<dim3(N2 / 32, K / 32), dim3(32, 8), 0, stream>>>(proj_w, wt_proj,
                                                              flag, K, N2);
  for (int c = 0; c < CH; ++c) {
    const size_t roff = (size_t)c * MC * 512;
    k_conv_x<<<MC * 512 / 2048, 256, 0, stream>>>((const float*)x + roff, xbc,
                                                  flag, MC * 512);
    // grid 6 x 100 = 600 blocks (%8==0, swizzle bijective)
    gemm_bt_bias<<<dim3(N1 / BN, MC / BM), 512, 0, stream>>>(
        (const u16*)x + roff, xbc, wt_qkv, bq, qkvc, flag, N1, K, 0);
    attn_win<<<(MC / 5) * 8 / 4, 256, 0, stream>>>(qkvc, (u16*)attnb + roff,
                                                   MC / 5);
  }
  // grid 2 x 400 = 800 blocks (%8==0)
  gemm_bt_bias<<<dim3(N2 / BN, M / BM), 512, 0, stream>>>(
      attnb, attnb, wt_proj, bp, d_out, flag, N2, K, 1);
}

// Round 4
// 781.562 us; speedup vs baseline: 1.2700x; 1.2387x over previous
//
#include <hip/hip_runtime.h>
#include <stdint.h>

// LocallyGroupedSelfAttention (B=512,N=200,C=512,NH=8,WS=5,HD=64).
// Dtype-robust: a sniff kernel detects fp32 vs packed-bf16 inputs at runtime;
// all math runs in bf16 MFMA either way; output written fp32 or bf16 per flag.
// Pipeline: sniff -> prep bias/weights(T) -> 4x [conv_x, qkv GEMM, window attn]
// -> proj GEMM. ws ~212 MB.
// R1: global_load_lds staging (m97) — marginal; K=512 is latency-bound.
// R3: 256x256 tile, 8 waves, 2-phase double-buffered LDS + XCD swizzle — −23us.
// R4: attn_win re-mapped: one wave per WINDOW (8 heads across lane groups,
// 8 d-elems/lane). Butterfly 3 levels within 8-lane groups: 75 DS-ops/window
// vs 1200 before (16x). Vectorized u16x8 loads/stores. GEMM untouched.

typedef unsigned short u16;
typedef __bf16 bf16_t;
typedef bf16_t bf16x8 __attribute__((ext_vector_type(8)));
typedef float f32x4 __attribute__((ext_vector_type(4)));
typedef u16 u16x8 __attribute__((ext_vector_type(8)));

__device__ __forceinline__ float b2f(u16 u) {
  return __uint_as_float(((uint32_t)u) << 16);
}
__device__ __forceinline__ u16 f2b(float f) {
  uint32_t u = __float_as_uint(f);
  u += 0x7FFFu + ((u >> 16) & 1u);  // RNE
  return (u16)(u >> 16);
}

// async global -> LDS, 16 B per lane; LDS dest is wave-uniform base + lane*16.
#define GLOAD_LDS16(g, l)                                     \
  __builtin_amdgcn_global_load_lds(                           \
      (const __attribute__((address_space(1))) void*)(g),     \
      (__attribute__((address_space(3))) void*)(l), 16, 0, 0)

// flag = 1 if x looks like fp32, 0 if packed bf16 pairs.
__global__ void k_sniff(const uint32_t* __restrict__ x,
                        uint32_t* __restrict__ flag) {
  if (threadIdx.x == 0 && blockIdx.x == 0) {
    int cnt = 0;
    for (int i = 0; i < 256; ++i) {
      uint32_t e = (x[i] >> 23) & 0xFFu;
      if (e >= 64u && e <= 192u) ++cnt;  // fp32 N(0,1) exponents land here
    }
    *flag = (cnt >= 128) ? 1u : 0u;
  }
}

__global__ void k_prep_bias(const void* __restrict__ qb,
                            const void* __restrict__ pb,
                            const uint32_t* __restrict__ flag,
                            u16* __restrict__ bq, u16* __restrict__ bp) {
  const bool f = (*flag) != 0;
  int i = blockIdx.x * 256 + threadIdx.x;
  if (i < 1536)
    bq[i] = f ? f2b(((const float*)qb)[i]) : ((const u16*)qb)[i];
  else {
    int j = i - 1536;
    if (j < 512) bp[j] = f ? f2b(((const float*)pb)[j]) : ((const u16*)pb)[j];
  }
}

// in[R][Cc] (fp32 or bf16 per flag) -> out[Cc][R] bf16. block (32,8).
__global__ void k_prep_w(const void* __restrict__ in, u16* __restrict__ out,
                         const uint32_t* __restrict__ flag, int R, int Cc) {
  __shared__ u16 tile[32][33];
  const bool f = (*flag) != 0;
  const int bx = blockIdx.x * 32, by = blockIdx.y * 32;
  const int tx = threadIdx.x, ty = threadIdx.y;
  for (int i = ty; i < 32; i += 8) {
    size_t idx = (size_t)(by + i) * Cc + bx + tx;
    tile[i][tx] = f ? f2b(((const float*)in)[idx]) : ((const u16*)in)[idx];
  }
  __syncthreads();
  for (int i = ty; i < 32; i += 8)
    out[(size_t)(bx + i) * R + by + tx] = tile[tx][i];
}

// fp32 -> bf16 chunk convert (no-op when inputs already bf16)
__global__ void k_conv_x(const float* __restrict__ x, u16* __restrict__ xb,
                         const uint32_t* __restrict__ flag, int n) {
  if ((*flag) == 0) return;
  int i = (blockIdx.x * 256 + threadIdx.x) * 8;
  if (i >= n) return;
  float4 a = *(const float4*)&x[i];
  float4 b = *(const float4*)&x[i + 4];
  u16x8 o;
  o[0] = f2b(a.x); o[1] = f2b(a.y); o[2] = f2b(a.z); o[3] = f2b(a.w);
  o[4] = f2b(b.x); o[5] = f2b(b.y); o[6] = f2b(b.z); o[7] = f2b(b.w);
  *(u16x8*)&xb[i] = o;
}

// ------------------------------------------------------------------- GEMM
// C[M][N] = A[M][K] @ Bt[N][K]^T + bias. 256x256 tile, BK=32, 8 waves 2Mx4N,
// per-wave output 128x64 (8x4 16x16x32 frags). Double-buffered LDS:
// stage step t+1 (4 global_load_lds/wave) BEFORE computing step t; single
// __syncthreads per step drains vmcnt late (load latency hidden by 32 MFMA).
// LDS 64 KB: [buf][A 256x32 | B 256x32] u16, linear rows (64 B) for gload_lds.
#define BM 256
#define BN 256
#define BK 32

__global__ __launch_bounds__(512, 2) void gemm_bt_bias(
    const u16* __restrict__ A0,  // A when flag==0 (bf16 world)
    const u16* __restrict__ A1,  // A when flag==1 (pre-converted bf16)
    const u16* __restrict__ Bt, const u16* __restrict__ bias,
    void* __restrict__ Cout, const uint32_t* __restrict__ flag,
    int N, int K, int out_f32_if_flag) {
  __shared__ u16 smem[32768];  // 64 KB: As0@0, Bs0@8192, As1@16384, Bs1@24576

  const bool f = (*flag) != 0;
  const u16* A = f ? A1 : A0;

  const int t = threadIdx.x;
  const int wave = t >> 6;         // 0..7
  const int lane = t & 63;
  const int waveM = wave >> 2;     // 0..1  -> M offset waveM*128
  const int waveN = wave & 3;      // 0..3  -> N offset waveN*64

  // T1: bijective XCD swizzle (grid sizes are multiples of 8 by construction)
  const int nbx = gridDim.x;
  const int nwg = nbx * gridDim.y;
  const int bid = blockIdx.y * nbx + blockIdx.x;
  const int cpx = nwg >> 3;
  const int swz = (bid & 7) * cpx + (bid >> 3);
  const int bm = (swz / nbx) * BM;
  const int bn = (swz % nbx) * BN;

  const int kq = (lane >> 4) * 8;  // K sub-offset for MFMA frag
  const int l15 = lane & 15;

  // Staging: one gload_lds = 64 lanes x 16 B = 1 KiB = 16 LDS rows of [*][32].
  // Chunk j covers rows [j*16, j*16+16); lane -> row j*16+(lane>>2),
  // u16 col (lane&3)*8. Wave w owns chunks {2w, 2w+1} of A and of B.
  const int srow = lane >> 2;
  const int scol = (lane & 3) * 8;
  const int j0 = wave * 2;

  const u16* Agp = &A[(size_t)(bm + j0 * 16 + srow) * K + scol];
  const u16* Bgp = &Bt[(size_t)(bn + j0 * 16 + srow) * K + scol];

#define STAGE(b, k0)                                              \
  {                                                               \
    u16* as_ = smem + (b) * 16384 + j0 * 512;                     \
    u16* bs_ = smem + (b) * 16384 + 8192 + j0 * 512;              \
    GLOAD_LDS16(Agp + (size_t)(k0), as_);                         \
    GLOAD_LDS16(Agp + (size_t)(k0) + 16 * (size_t)K, as_ + 512);  \
    GLOAD_LDS16(Bgp + (size_t)(k0), bs_);                         \
    GLOAD_LDS16(Bgp + (size_t)(k0) + 16 * (size_t)K, bs_ + 512);  \
  }

  f32x4 acc[8][4] = {};

#define COMPUTE(b)                                                        \
  {                                                                       \
    const u16* As_ = smem + (b) * 16384;                                  \
    const u16* Bs_ = As_ + 8192;                                          \
    bf16x8 af[8], bfr[4];                                                 \
    _Pragma("unroll") for (int i = 0; i < 8; ++i)                         \
        af[i] = *(const bf16x8*)&As_[(waveM * 128 + i * 16 + l15) * BK + kq]; \
    _Pragma("unroll") for (int j = 0; j < 4; ++j)                         \
        bfr[j] = *(const bf16x8*)&Bs_[(waveN * 64 + j * 16 + l15) * BK + kq]; \
    _Pragma("unroll") for (int i = 0; i < 8; ++i)                         \
        _Pragma("unroll") for (int j = 0; j < 4; ++j)                     \
            acc[i][j] = __builtin_amdgcn_mfma_f32_16x16x32_bf16(          \
                af[i], bfr[j], acc[i][j], 0, 0, 0);                       \
  }

  const int NSTEP = K / BK;  // 16 (even)
  STAGE(0, 0);
  __syncthreads();  // drain: buf0 resident
  for (int s = 0; s + 2 < NSTEP; s += 2) {
    STAGE(1, (s + 1) * BK);   // issue next while computing current
    COMPUTE(0);
    __syncthreads();          // late drain: buf1 ready, buf0 reads done
    STAGE(0, (s + 2) * BK);
    COMPUTE(1);
    __syncthreads();
  }
  STAGE(1, (NSTEP - 1) * BK);
  COMPUTE(0);
  __syncthreads();
  COMPUTE(1);
  __syncthreads();  // LDS now reusable for epilogue repack

  float biasf[4];
#pragma unroll
  for (int j = 0; j < 4; ++j)
    biasf[j] = b2f(bias[bn + waveN * 64 + j * 16 + l15]);

  // C/D frag: col = lane&15, row = (lane>>4)*4 + reg  [m89/m91]
  if (out_f32_if_flag && f) {
    float* C = (float*)Cout;
#pragma unroll
    for (int i = 0; i < 8; ++i) {
      const int row0 = waveM * 128 + i * 16 + (lane >> 4) * 4;
#pragma unroll
      for (int j = 0; j < 4; ++j) {
        const int col = waveN * 64 + j * 16 + l15;
#pragma unroll
        for (int r = 0; r < 4; ++r)
          C[(size_t)(bm + row0 + r) * N + bn + col] = acc[i][j][r] + biasf[j];
      }
    }
  } else {
    // bf16 out: repack 128 rows at a time through LDS (64 KB = 128x256 u16)
    u16* C = (u16*)Cout;
#pragma unroll
    for (int h = 0; h < 2; ++h) {
      if (waveM == h) {
#pragma unroll
        for (int i = 0; i < 8; ++i) {
          const int row0 = i * 16 + (lane >> 4) * 4;  // 0..127
#pragma unroll
          for (int j = 0; j < 4; ++j) {
            const int col = waveN * 64 + j * 16 + l15;
#pragma unroll
            for (int r = 0; r < 4; ++r)
              smem[(row0 + r) * 256 + col] = f2b(acc[i][j][r] + biasf[j]);
          }
        }
      }
      __syncthreads();
#pragma unroll
      for (int s = 0; s < 8; ++s) {
        const int vi = s * 512 + t;
        const int row = vi >> 5;           // 0..127
        const int col = (vi & 31) * 8;     // 0..248
        u16x8 v = *(const u16x8*)&smem[row * 256 + col];
        *(u16x8*)&C[(size_t)(bm + h * 128 + row) * N + bn + col] = v;
      }
      __syncthreads();
    }
  }
#undef STAGE
#undef COMPUTE
}

// ------------------------------------------------------------- attention
// qkv[rows][1536]: Q [0,512), K [512,1024), V [1024,1536); head h at h*64.
// R4: one wave per WINDOW. lane = h*8 + dg: head h = lane>>3, d-elems
// dg*8..dg*8+7. Dot over d=64 = 8 local FMA + 3-level butterfly within the
// 8-lane d-group. All loads/stores u16x8 (16 B/lane, coalesced 1 KB rows).
__global__ __launch_bounds__(256) void attn_win(const u16* __restrict__ qkv,
                                                u16* __restrict__ o,
                                                int nwin) {
  const int w = blockIdx.x * 4 + (threadIdx.x >> 6);
  if (w >= nwin) return;
  const int lane = threadIdx.x & 63;
  const int h = lane >> 3;        // head 0..7
  const int d0 = (lane & 7) * 8;  // d-group base 0..56
  const u16* base = qkv + (size_t)w * (5 * 1536) + h * 64 + d0;

  float qf[5][8], kf[5][8], vf[5][8];
#pragma unroll
  for (int i = 0; i < 5; ++i) {
    u16x8 vq = *(const u16x8*)&base[i * 1536];
    u16x8 vk = *(const u16x8*)&base[i * 1536 + 512];
    u16x8 vv = *(const u16x8*)&base[i * 1536 + 1024];
#pragma unroll
    for (int e = 0; e < 8; ++e) {
      qf[i][e] = b2f(vq[e]);
      kf[i][e] = b2f(vk[e]);
      vf[i][e] = b2f(vv[e]);
    }
  }

  // partial scores over this lane's 8 d-elems
  float s[5][5];
#pragma unroll
  for (int i = 0; i < 5; ++i)
#pragma unroll
    for (int j = 0; j < 5; ++j) {
      float acc = 0.f;
#pragma unroll
      for (int e = 0; e < 8; ++e) acc += qf[i][e] * kf[j][e];
      s[i][j] = acc;
    }
  // butterfly within 8-lane d-group (lane bits 0-2): full dot over d=64
#pragma unroll
  for (int off = 1; off < 8; off <<= 1) {
#pragma unroll
    for (int i = 0; i < 5; ++i)
#pragma unroll
      for (int j = 0; j < 5; ++j) s[i][j] += __shfl_xor(s[i][j], off, 64);
  }

  const float SCALE = 0.125f;  // 64^-0.5
  u16* ob = o + (size_t)w * (5 * 512) + h * 64 + d0;
#pragma unroll
  for (int i = 0; i < 5; ++i) {
    float m = s[i][0];
#pragma unroll
    for (int j = 1; j < 5; ++j) m = fmaxf(m, s[i][j]);
    float e0[5], l = 0.f;
#pragma unroll
    for (int j = 0; j < 5; ++j) {
      e0[j] = __expf((s[i][j] - m) * SCALE);
      l += e0[j];
    }
    const float rl = 1.f / l;
    u16x8 out;
#pragma unroll
    for (int e = 0; e < 8; ++e) {
      float acc = 0.f;
#pragma unroll
      for (int j = 0; j < 5; ++j) acc += e0[j] * vf[j][e];
      out[e] = f2b(acc * rl);
    }
    *(u16x8*)&ob[i * 512] = out;
  }
}

// ---------------------------------------------------------------- launch
extern "C" void kernel_launch(void* const* d_in, const int* in_sizes, int n_in,
                              void* d_out, int out_size, void* d_ws,
                              size_t ws_size, hipStream_t stream) {
  const void* x      = d_in[0];  // [102400][512]  fp32 or bf16
  const void* qkv_w  = d_in[1];  // [512][1536]
  const void* qkv_b  = d_in[2];  // [1536]
  const void* proj_w = d_in[3];  // [512][512]
  const void* proj_b = d_in[4];  // [512]

  const int M = 102400, K = 512, N1 = 1536, N2 = 512;
  const int CH = 4, MC = M / CH;  // 25600 rows/chunk

  char* ws = (char*)d_ws;
  uint32_t* flag = (uint32_t*)ws;                       // @0
  u16* bq      = (u16*)(ws + 256);                      // 1536*2
  u16* bp      = (u16*)(ws + 256 + 3072);               // 512*2
  u16* wt_qkv  = (u16*)(ws + 8192);                     // 1536*512*2
  u16* wt_proj = (u16*)(ws + 8192 + 1572864);           // 512*512*2
  u16* attnb   = (u16*)(ws + 8192 + 1572864 + 524288);  // M*512*2 = 104.9 MB
  u16* qkvc    = (u16*)((char*)attnb + (size_t)M * 512 * 2);   // MC*1536*2
  u16* xbc     = (u16*)((char*)qkvc + (size_t)MC * 1536 * 2);  // MC*512*2
  // total ~212 MB

  k_sniff<<<1, 64, 0, stream>>>((const uint32_t*)x, flag);
  k_prep_bias<<<8, 256, 0, stream>>>(qkv_b, proj_b, flag, bq, bp);
  k_prep_w<<<dim3(N1 / 32, K / 32), dim3(32, 8), 0, stream>>>(qkv_w, wt_qkv,
                                                              flag, K, N1);
  k_prep_w<<<dim3(N2 / 32, K / 32), dim3(32, 8), 0, stream>>>(proj_w, wt_proj,
                                                              flag, K, N2);
  for (int c = 0; c < CH; ++c) {
    const size_t roff = (size_t)c * MC * 512;
    k_conv_x<<<MC * 512 / 2048, 256, 0, stream>>>((const float*)x + roff, xbc,
                                                  flag, MC * 512);
    // grid 6 x 100 = 600 blocks (%8==0, swizzle bijective)
    gemm_bt_bias<<<dim3(N1 / BN, MC / BM), 512, 0, stream>>>(
        (const u16*)x + roff, xbc, wt_qkv, bq, qkvc, flag, N1, K, 0);
    // one wave per window: MC/5 = 5120 windows -> 1280 blocks of 4 waves
    attn_win<<<(MC / 5) / 4, 256, 0, stream>>>(qkvc, (u16*)attnb + roff,
                                               MC / 5);
  }
  // grid 2 x 400 = 800 blocks (%8==0)
  gemm_bt_bias<<<dim3(N2 / BN, M / BM), 512, 0, stream>>>(
      attnb, attnb, wt_proj, bp, d_out, flag, N2, K, 1);
}

// Round 5
// 777.997 us; speedup vs baseline: 1.2758x; 1.0046x over previous
//
#include <hip/hip_runtime.h>
#include <stdint.h>

// LocallyGroupedSelfAttention (B=512,N=200,C=512,NH=8,WS=5,HD=64).
// Dtype-robust: sniff detects fp32 vs packed-bf16 at runtime; all math bf16
// MFMA; output fp32 or bf16 per flag.
// R1: global_load_lds staging (m97) — marginal; K=512 latency-bound.
// R3: 256x256 tile, 8 waves, 2-phase dbuf LDS + XCD swizzle — −23us.
// R4: attn one-wave-per-window, 8-lane-group butterfly (16x fewer DS ops),
//     u16x8 vector loads — −187us (matched prediction).
// R5: launch-geometry round: dynamic un-chunking (CH from ws_size; CH=1 if
//     ~527MB fits -> single conv/qkv/attn dispatches, kills 600-block round
//     quantization), sniff+bias merged, prep_w x2 merged. 18 -> 6 launches.
//     GEMM + attn kernels byte-identical to R4.

typedef unsigned short u16;
typedef __bf16 bf16_t;
typedef bf16_t bf16x8 __attribute__((ext_vector_type(8)));
typedef float f32x4 __attribute__((ext_vector_type(4)));
typedef u16 u16x8 __attribute__((ext_vector_type(8)));

__device__ __forceinline__ float b2f(u16 u) {
  return __uint_as_float(((uint32_t)u) << 16);
}
__device__ __forceinline__ u16 f2b(float f) {
  uint32_t u = __float_as_uint(f);
  u += 0x7FFFu + ((u >> 16) & 1u);  // RNE
  return (u16)(u >> 16);
}

// async global -> LDS, 16 B per lane; LDS dest is wave-uniform base + lane*16.
#define GLOAD_LDS16(g, l)                                     \
  __builtin_amdgcn_global_load_lds(                           \
      (const __attribute__((address_space(1))) void*)(g),     \
      (__attribute__((address_space(3))) void*)(l), 16, 0, 0)

// Merged: flag sniff (thread 0) + bias conversion (all threads). 1 block/1024.
__global__ void k_sniff_bias(const uint32_t* __restrict__ x,
                             const void* __restrict__ qb,
                             const void* __restrict__ pb,
                             uint32_t* __restrict__ flag,
                             u16* __restrict__ bq, u16* __restrict__ bp) {
  __shared__ uint32_t fsh;
  if (threadIdx.x == 0) {
    int cnt = 0;
    for (int i = 0; i < 256; ++i) {
      uint32_t e = (x[i] >> 23) & 0xFFu;
      if (e >= 64u && e <= 192u) ++cnt;  // fp32 N(0,1) exponents land here
    }
    uint32_t fl = (cnt >= 128) ? 1u : 0u;
    *flag = fl;
    fsh = fl;
  }
  __syncthreads();
  const bool f = fsh != 0;
  for (int i = threadIdx.x; i < 2048; i += 1024) {
    if (i < 1536)
      bq[i] = f ? f2b(((const float*)qb)[i]) : ((const u16*)qb)[i];
    else {
      int j = i - 1536;
      bp[j] = f ? f2b(((const float*)pb)[j]) : ((const u16*)pb)[j];
    }
  }
}

// Merged transpose of both weights: in[512][Cc] -> out[Cc][512] bf16.
// grid (48+16, 16), block (32,8). bx<48 -> qkv (Cc=1536), else proj (Cc=512).
__global__ void k_prep_w2(const void* __restrict__ qkvw,
                          const void* __restrict__ projw,
                          u16* __restrict__ wq, u16* __restrict__ wp,
                          const uint32_t* __restrict__ flag) {
  __shared__ u16 tile[32][33];
  const bool f = (*flag) != 0;
  int bxi = blockIdx.x;
  const void* in;
  u16* out;
  int Cc;
  if (bxi < 48) {
    in = qkvw; out = wq; Cc = 1536;
  } else {
    bxi -= 48; in = projw; out = wp; Cc = 512;
  }
  const int R = 512;
  const int bx = bxi * 32, by = blockIdx.y * 32;
  const int tx = threadIdx.x, ty = threadIdx.y;
  for (int i = ty; i < 32; i += 8) {
    size_t idx = (size_t)(by + i) * Cc + bx + tx;
    tile[i][tx] = f ? f2b(((const float*)in)[idx]) : ((const u16*)in)[idx];
  }
  __syncthreads();
  for (int i = ty; i < 32; i += 8)
    out[(size_t)(bx + i) * R + by + tx] = tile[tx][i];
}

// fp32 -> bf16 chunk convert (no-op when inputs already bf16)
__global__ void k_conv_x(const float* __restrict__ x, u16* __restrict__ xb,
                         const uint32_t* __restrict__ flag, int n) {
  if ((*flag) == 0) return;
  int i = (blockIdx.x * 256 + threadIdx.x) * 8;
  if (i >= n) return;
  float4 a = *(const float4*)&x[i];
  float4 b = *(const float4*)&x[i + 4];
  u16x8 o;
  o[0] = f2b(a.x); o[1] = f2b(a.y); o[2] = f2b(a.z); o[3] = f2b(a.w);
  o[4] = f2b(b.x); o[5] = f2b(b.y); o[6] = f2b(b.z); o[7] = f2b(b.w);
  *(u16x8*)&xb[i] = o;
}

// ------------------------------------------------------------------- GEMM
// C[M][N] = A[M][K] @ Bt[N][K]^T + bias. 256x256 tile, BK=32, 8 waves 2Mx4N,
// per-wave output 128x64 (8x4 16x16x32 frags). Double-buffered LDS:
// stage step t+1 (4 global_load_lds/wave) BEFORE computing step t; single
// __syncthreads per step drains vmcnt late (load latency hidden by 32 MFMA).
// LDS 64 KB: [buf][A 256x32 | B 256x32] u16, linear rows (64 B) for gload_lds.
#define BM 256
#define BN 256
#define BK 32

__global__ __launch_bounds__(512, 2) void gemm_bt_bias(
    const u16* __restrict__ A0,  // A when flag==0 (bf16 world)
    const u16* __restrict__ A1,  // A when flag==1 (pre-converted bf16)
    const u16* __restrict__ Bt, const u16* __restrict__ bias,
    void* __restrict__ Cout, const uint32_t* __restrict__ flag,
    int N, int K, int out_f32_if_flag) {
  __shared__ u16 smem[32768];  // 64 KB: As0@0, Bs0@8192, As1@16384, Bs1@24576

  const bool f = (*flag) != 0;
  const u16* A = f ? A1 : A0;

  const int t = threadIdx.x;
  const int wave = t >> 6;         // 0..7
  const int lane = t & 63;
  const int waveM = wave >> 2;     // 0..1  -> M offset waveM*128
  const int waveN = wave & 3;      // 0..3  -> N offset waveN*64

  // T1: bijective XCD swizzle (grid sizes are multiples of 8 by construction)
  const int nbx = gridDim.x;
  const int nwg = nbx * gridDim.y;
  const int bid = blockIdx.y * nbx + blockIdx.x;
  const int cpx = nwg >> 3;
  const int swz = (bid & 7) * cpx + (bid >> 3);
  const int bm = (swz / nbx) * BM;
  const int bn = (swz % nbx) * BN;

  const int kq = (lane >> 4) * 8;  // K sub-offset for MFMA frag
  const int l15 = lane & 15;

  // Staging: one gload_lds = 64 lanes x 16 B = 1 KiB = 16 LDS rows of [*][32].
  // Chunk j covers rows [j*16, j*16+16); lane -> row j*16+(lane>>2),
  // u16 col (lane&3)*8. Wave w owns chunks {2w, 2w+1} of A and of B.
  const int srow = lane >> 2;
  const int scol = (lane & 3) * 8;
  const int j0 = wave * 2;

  const u16* Agp = &A[(size_t)(bm + j0 * 16 + srow) * K + scol];
  const u16* Bgp = &Bt[(size_t)(bn + j0 * 16 + srow) * K + scol];

#define STAGE(b, k0)                                              \
  {                                                               \
    u16* as_ = smem + (b) * 16384 + j0 * 512;                     \
    u16* bs_ = smem + (b) * 16384 + 8192 + j0 * 512;              \
    GLOAD_LDS16(Agp + (size_t)(k0), as_);                         \
    GLOAD_LDS16(Agp + (size_t)(k0) + 16 * (size_t)K, as_ + 512);  \
    GLOAD_LDS16(Bgp + (size_t)(k0), bs_);                         \
    GLOAD_LDS16(Bgp + (size_t)(k0) + 16 * (size_t)K, bs_ + 512);  \
  }

  f32x4 acc[8][4] = {};

#define COMPUTE(b)                                                        \
  {                                                                       \
    const u16* As_ = smem + (b) * 16384;                                  \
    const u16* Bs_ = As_ + 8192;                                          \
    bf16x8 af[8], bfr[4];                                                 \
    _Pragma("unroll") for (int i = 0; i < 8; ++i)                         \
        af[i] = *(const bf16x8*)&As_[(waveM * 128 + i * 16 + l15) * BK + kq]; \
    _Pragma("unroll") for (int j = 0; j < 4; ++j)                         \
        bfr[j] = *(const bf16x8*)&Bs_[(waveN * 64 + j * 16 + l15) * BK + kq]; \
    _Pragma("unroll") for (int i = 0; i < 8; ++i)                         \
        _Pragma("unroll") for (int j = 0; j < 4; ++j)                     \
            acc[i][j] = __builtin_amdgcn_mfma_f32_16x16x32_bf16(          \
                af[i], bfr[j], acc[i][j], 0, 0, 0);                       \
  }

  const int NSTEP = K / BK;  // 16 (even)
  STAGE(0, 0);
  __syncthreads();  // drain: buf0 resident
  for (int s = 0; s + 2 < NSTEP; s += 2) {
    STAGE(1, (s + 1) * BK);   // issue next while computing current
    COMPUTE(0);
    __syncthreads();          // late drain: buf1 ready, buf0 reads done
    STAGE(0, (s + 2) * BK);
    COMPUTE(1);
    __syncthreads();
  }
  STAGE(1, (NSTEP - 1) * BK);
  COMPUTE(0);
  __syncthreads();
  COMPUTE(1);
  __syncthreads();  // LDS now reusable for epilogue repack

  float biasf[4];
#pragma unroll
  for (int j = 0; j < 4; ++j)
    biasf[j] = b2f(bias[bn + waveN * 64 + j * 16 + l15]);

  // C/D frag: col = lane&15, row = (lane>>4)*4 + reg  [m89/m91]
  if (out_f32_if_flag && f) {
    float* C = (float*)Cout;
#pragma unroll
    for (int i = 0; i < 8; ++i) {
      const int row0 = waveM * 128 + i * 16 + (lane >> 4) * 4;
#pragma unroll
      for (int j = 0; j < 4; ++j) {
        const int col = waveN * 64 + j * 16 + l15;
#pragma unroll
        for (int r = 0; r < 4; ++r)
          C[(size_t)(bm + row0 + r) * N + bn + col] = acc[i][j][r] + biasf[j];
      }
    }
  } else {
    // bf16 out: repack 128 rows at a time through LDS (64 KB = 128x256 u16)
    u16* C = (u16*)Cout;
#pragma unroll
    for (int h = 0; h < 2; ++h) {
      if (waveM == h) {
#pragma unroll
        for (int i = 0; i < 8; ++i) {
          const int row0 = i * 16 + (lane >> 4) * 4;  // 0..127
#pragma unroll
          for (int j = 0; j < 4; ++j) {
            const int col = waveN * 64 + j * 16 + l15;
#pragma unroll
            for (int r = 0; r < 4; ++r)
              smem[(row0 + r) * 256 + col] = f2b(acc[i][j][r] + biasf[j]);
          }
        }
      }
      __syncthreads();
#pragma unroll
      for (int s = 0; s < 8; ++s) {
        const int vi = s * 512 + t;
        const int row = vi >> 5;           // 0..127
        const int col = (vi & 31) * 8;     // 0..248
        u16x8 v = *(const u16x8*)&smem[row * 256 + col];
        *(u16x8*)&C[(size_t)(bm + h * 128 + row) * N + bn + col] = v;
      }
      __syncthreads();
    }
  }
#undef STAGE
#undef COMPUTE
}

// ------------------------------------------------------------- attention
// qkv[rows][1536]: Q [0,512), K [512,1024), V [1024,1536); head h at h*64.
// One wave per WINDOW. lane = h*8 + dg: head h = lane>>3, d-elems
// dg*8..dg*8+7. Dot over d=64 = 8 local FMA + 3-level butterfly within the
// 8-lane d-group. All loads/stores u16x8 (16 B/lane, coalesced 1 KB rows).
__global__ __launch_bounds__(256) void attn_win(const u16* __restrict__ qkv,
                                                u16* __restrict__ o,
                                                int nwin) {
  const int w = blockIdx.x * 4 + (threadIdx.x >> 6);
  if (w >= nwin) return;
  const int lane = threadIdx.x & 63;
  const int h = lane >> 3;        // head 0..7
  const int d0 = (lane & 7) * 8;  // d-group base 0..56
  const u16* base = qkv + (size_t)w * (5 * 1536) + h * 64 + d0;

  float qf[5][8], kf[5][8], vf[5][8];
#pragma unroll
  for (int i = 0; i < 5; ++i) {
    u16x8 vq = *(const u16x8*)&base[i * 1536];
    u16x8 vk = *(const u16x8*)&base[i * 1536 + 512];
    u16x8 vv = *(const u16x8*)&base[i * 1536 + 1024];
#pragma unroll
    for (int e = 0; e < 8; ++e) {
      qf[i][e] = b2f(vq[e]);
      kf[i][e] = b2f(vk[e]);
      vf[i][e] = b2f(vv[e]);
    }
  }

  // partial scores over this lane's 8 d-elems
  float s[5][5];
#pragma unroll
  for (int i = 0; i < 5; ++i)
#pragma unroll
    for (int j = 0; j < 5; ++j) {
      float acc = 0.f;
#pragma unroll
      for (int e = 0; e < 8; ++e) acc += qf[i][e] * kf[j][e];
      s[i][j] = acc;
    }
  // butterfly within 8-lane d-group (lane bits 0-2): full dot over d=64
#pragma unroll
  for (int off = 1; off < 8; off <<= 1) {
#pragma unroll
    for (int i = 0; i < 5; ++i)
#pragma unroll
      for (int j = 0; j < 5; ++j) s[i][j] += __shfl_xor(s[i][j], off, 64);
  }

  const float SCALE = 0.125f;  // 64^-0.5
  u16* ob = o + (size_t)w * (5 * 512) + h * 64 + d0;
#pragma unroll
  for (int i = 0; i < 5; ++i) {
    float m = s[i][0];
#pragma unroll
    for (int j = 1; j < 5; ++j) m = fmaxf(m, s[i][j]);
    float e0[5], l = 0.f;
#pragma unroll
    for (int j = 0; j < 5; ++j) {
      e0[j] = __expf((s[i][j] - m) * SCALE);
      l += e0[j];
    }
    const float rl = 1.f / l;
    u16x8 out;
#pragma unroll
    for (int e = 0; e < 8; ++e) {
      float acc = 0.f;
#pragma unroll
      for (int j = 0; j < 5; ++j) acc += e0[j] * vf[j][e];
      out[e] = f2b(acc * rl);
    }
    *(u16x8*)&ob[i * 512] = out;
  }
}

// ---------------------------------------------------------------- launch
extern "C" void kernel_launch(void* const* d_in, const int* in_sizes, int n_in,
                              void* d_out, int out_size, void* d_ws,
                              size_t ws_size, hipStream_t stream) {
  const void* x      = d_in[0];  // [102400][512]  fp32 or bf16
  const void* qkv_w  = d_in[1];  // [512][1536]
  const void* qkv_b  = d_in[2];  // [1536]
  const void* proj_w = d_in[3];  // [512][512]
  const void* proj_b = d_in[4];  // [512]

  const int M = 102400, K = 512, N1 = 1536, N2 = 512;

  // Dynamic chunking: CH=1 needs ~527 MB of ws (fills suggest ~839 MB avail);
  // fall back to 2 / 4 if the harness gives less.
  const size_t fixed = 8192 + 1572864 + 524288 + (size_t)M * 512 * 2;
  int CH = 4;
  if (ws_size >= fixed + (size_t)M * 2048 * 2) CH = 1;
  else if (ws_size >= fixed + (size_t)(M / 2) * 2048 * 2) CH = 2;
  const int MC = M / CH;

  char* ws = (char*)d_ws;
  uint32_t* flag = (uint32_t*)ws;                       // @0
  u16* bq      = (u16*)(ws + 256);                      // 1536*2
  u16* bp      = (u16*)(ws + 256 + 3072);               // 512*2
  u16* wt_qkv  = (u16*)(ws + 8192);                     // 1536*512*2
  u16* wt_proj = (u16*)(ws + 8192 + 1572864);           // 512*512*2
  u16* attnb   = (u16*)(ws + 8192 + 1572864 + 524288);  // M*512*2 = 104.9 MB
  u16* qkvc    = (u16*)((char*)attnb + (size_t)M * 512 * 2);   // MC*1536*2
  u16* xbc     = (u16*)((char*)qkvc + (size_t)MC * 1536 * 2);  // MC*512*2

  k_sniff_bias<<<1, 1024, 0, stream>>>((const uint32_t*)x, qkv_b, proj_b, flag,
                                       bq, bp);
  k_prep_w2<<<dim3(64, 16), dim3(32, 8), 0, stream>>>(qkv_w, proj_w, wt_qkv,
                                                      wt_proj, flag);
  for (int c = 0; c < CH; ++c) {
    const size_t roff = (size_t)c * MC * 512;
    k_conv_x<<<MC * 512 / 2048, 256, 0, stream>>>((const float*)x + roff, xbc,
                                                  flag, MC * 512);
    // qkv grid: (1536/256) x (MC/256); CH=1 -> 6x400=2400 blocks (%8==0)
    gemm_bt_bias<<<dim3(N1 / BN, MC / BM), 512, 0, stream>>>(
        (const u16*)x + roff, xbc, wt_qkv, bq, qkvc, flag, N1, K, 0);
    // one wave per window: MC/5 windows, 4 waves/block
    attn_win<<<(MC / 5) / 4, 256, 0, stream>>>(qkvc, (u16*)attnb + roff,
                                               MC / 5);
  }
  // proj grid 2 x 400 = 800 blocks (%8==0)
  gemm_bt_bias<<<dim3(N2 / BN, M / BM), 512, 0, stream>>>(
      attnb, attnb, wt_proj, bp, d_out, flag, N2, K, 1);
}

// Round 7
// 768.726 us; speedup vs baseline: 1.2912x; 1.0121x over previous
//
#include <hip/hip_runtime.h>
#include <stdint.h>

// LocallyGroupedSelfAttention (B=512,N=200,C=512,NH=8,WS=5,HD=64).
// R4: attn one-wave-per-window (−187us). R5: un-chunk + launch merge (qkv GEMM
// now visible: 252us, 639 TF = 2-phase structure ceiling, 19.7M LDS conflicts).
// R6: GEMM inner loop rebuilt as 4-phase interleaved pipeline (T3/T4/T5/T2):
//   BK=64, 2 LDS bufs (128KB), per tile 4 phases {12 ds_read | stage-next |
//   s_barrier | setprio+16 MFMA | s_barrier}, one vmcnt(0)/tile, subtiled
//   [16r][32B] LDS layout (bank-balanced: wave's 12 b128 reads cover
//   contiguous 1KB = throughput floor), launch_bounds(512,1).
// R7: identical resubmit (R6 bench failed on GPU acquisition, no data).

typedef unsigned short u16;
typedef __bf16 bf16_t;
typedef bf16_t bf16x8 __attribute__((ext_vector_type(8)));
typedef float f32x4 __attribute__((ext_vector_type(4)));
typedef u16 u16x8 __attribute__((ext_vector_type(8)));

__device__ __forceinline__ float b2f(u16 u) {
  return __uint_as_float(((uint32_t)u) << 16);
}
__device__ __forceinline__ u16 f2b(float f) {
  uint32_t u = __float_as_uint(f);
  u += 0x7FFFu + ((u >> 16) & 1u);  // RNE
  return (u16)(u >> 16);
}

// async global -> LDS, 16 B per lane; LDS dest is wave-uniform base + lane*16.
#define GLOAD_LDS16(g, l)                                     \
  __builtin_amdgcn_global_load_lds(                           \
      (const __attribute__((address_space(1))) void*)(g),     \
      (__attribute__((address_space(3))) void*)(l), 16, 0, 0)

// Merged: flag sniff (thread 0) + bias conversion (all threads). 1 block/1024.
__global__ void k_sniff_bias(const uint32_t* __restrict__ x,
                             const void* __restrict__ qb,
                             const void* __restrict__ pb,
                             uint32_t* __restrict__ flag,
                             u16* __restrict__ bq, u16* __restrict__ bp) {
  __shared__ uint32_t fsh;
  if (threadIdx.x == 0) {
    int cnt = 0;
    for (int i = 0; i < 256; ++i) {
      uint32_t e = (x[i] >> 23) & 0xFFu;
      if (e >= 64u && e <= 192u) ++cnt;  // fp32 N(0,1) exponents land here
    }
    uint32_t fl = (cnt >= 128) ? 1u : 0u;
    *flag = fl;
    fsh = fl;
  }
  __syncthreads();
  const bool f = fsh != 0;
  for (int i = threadIdx.x; i < 2048; i += 1024) {
    if (i < 1536)
      bq[i] = f ? f2b(((const float*)qb)[i]) : ((const u16*)qb)[i];
    else {
      int j = i - 1536;
      bp[j] = f ? f2b(((const float*)pb)[j]) : ((const u16*)pb)[j];
    }
  }
}

// Merged transpose of both weights: in[512][Cc] -> out[Cc][512] bf16.
// grid (48+16, 16), block (32,8). bx<48 -> qkv (Cc=1536), else proj (Cc=512).
__global__ void k_prep_w2(const void* __restrict__ qkvw,
                          const void* __restrict__ projw,
                          u16* __restrict__ wq, u16* __restrict__ wp,
                          const uint32_t* __restrict__ flag) {
  __shared__ u16 tile[32][33];
  const bool f = (*flag) != 0;
  int bxi = blockIdx.x;
  const void* in;
  u16* out;
  int Cc;
  if (bxi < 48) {
    in = qkvw; out = wq; Cc = 1536;
  } else {
    bxi -= 48; in = projw; out = wp; Cc = 512;
  }
  const int R = 512;
  const int bx = bxi * 32, by = blockIdx.y * 32;
  const int tx = threadIdx.x, ty = threadIdx.y;
  for (int i = ty; i < 32; i += 8) {
    size_t idx = (size_t)(by + i) * Cc + bx + tx;
    tile[i][tx] = f ? f2b(((const float*)in)[idx]) : ((const u16*)in)[idx];
  }
  __syncthreads();
  for (int i = ty; i < 32; i += 8)
    out[(size_t)(bx + i) * R + by + tx] = tile[tx][i];
}

// fp32 -> bf16 chunk convert (no-op when inputs already bf16)
__global__ void k_conv_x(const float* __restrict__ x, u16* __restrict__ xb,
                         const uint32_t* __restrict__ flag, int n) {
  if ((*flag) == 0) return;
  int i = (blockIdx.x * 256 + threadIdx.x) * 8;
  if (i >= n) return;
  float4 a = *(const float4*)&x[i];
  float4 b = *(const float4*)&x[i + 4];
  u16x8 o;
  o[0] = f2b(a.x); o[1] = f2b(a.y); o[2] = f2b(a.z); o[3] = f2b(a.w);
  o[4] = f2b(b.x); o[5] = f2b(b.y); o[6] = f2b(b.z); o[7] = f2b(b.w);
  *(u16x8*)&xb[i] = o;
}

// ------------------------------------------------------------------- GEMM
// C[M][N] = A[M][K] @ Bt[N][K]^T + bias. 256x256 tile, BK=64, 8 waves 2Mx4N,
// per-wave output 128x64. 4-phase pipeline, subtiled LDS (see header).
// LDS u16 map: buf b at b*32768: A subtiled 16384 u16, then B 16384 u16.
// Subtile layout per (rowgrp rg of 16 rows, K-half ks of 32):
//   addr = rg*1024 + ks*512 + cs*256 + r15*16 + co*8 + (k&7)
//   (cs = (k>>4)&1 within half, co = (k>>3)&1). Stage lane-map and frag
//   read rdOff are this same permutation (round-trip verified).
#define BM 256
#define BN 256

__global__ __launch_bounds__(512, 1) void gemm_bt_bias(
    const u16* __restrict__ A0,  // A when flag==0 (bf16 world)
    const u16* __restrict__ A1,  // A when flag==1 (pre-converted bf16)
    const u16* __restrict__ Bt, const u16* __restrict__ bias,
    void* __restrict__ Cout, const uint32_t* __restrict__ flag,
    int N, int K, int out_f32_if_flag) {
  __shared__ u16 smem[65536];  // 128 KB

  const bool f = (*flag) != 0;
  const u16* A = f ? A1 : A0;

  const int t = threadIdx.x;
  const int wave = t >> 6;         // 0..7
  const int lane = t & 63;
  const int waveM = wave >> 2;     // 0..1  -> M offset waveM*128
  const int waveN = wave & 3;      // 0..3  -> N offset waveN*64

  // T1: bijective XCD swizzle (grid sizes are multiples of 8 by construction)
  const int nbx = gridDim.x;
  const int nwg = nbx * gridDim.y;
  const int bid = blockIdx.y * nbx + blockIdx.x;
  const int cpx = nwg >> 3;
  const int swz = (bid & 7) * cpx + (bid >> 3);
  const int bm = (swz / nbx) * BM;
  const int bn = (swz % nbx) * BN;

  const int l15 = lane & 15;
  // frag ds_read lane offset (u16): cs-local 256*(lane>>5&1) + row 16*l15
  //   + 8*(lane>>4&1); + ks*512 + (rowgrp)*1024 at use site.
  const int rdOff = ((lane >> 5) & 1) * 256 + l15 * 16 + ((lane >> 4) & 1) * 8;
  // stage lane mapping: chunk c = wave*4+q covers LDS [c*512,(c+1)*512) u16;
  // lane -> row (c>>1)*16 + ((lane>>1)&15), u16 col (c&1)*32
  //   + ((lane>>5)&1)*16 + (lane&1)*8  (within the 64-wide K-tile).
  const int rowS = (lane >> 1) & 15;
  const int colS = ((lane >> 5) & 1) * 16 + (lane & 1) * 8;
  const u16* AgS[4];
  const u16* BgS[4];
#pragma unroll
  for (int q = 0; q < 4; ++q) {
    const int c = wave * 4 + q, g = c >> 1, p = c & 1;
    AgS[q] = &A[(size_t)(bm + g * 16 + rowS) * K + p * 32 + colS];
    BgS[q] = &Bt[(size_t)(bn + g * 16 + rowS) * K + p * 32 + colS];
  }

  f32x4 acc[8][4] = {};
  const int NT = K / 64;  // 8

#define STAGE_OP(PTRS, dstU16, kN)                                          \
  {                                                                         \
    _Pragma("unroll") for (int q = 0; q < 4; ++q)                           \
        GLOAD_LDS16(PTRS[q] + (kN), &smem[(dstU16) + (wave * 4 + q) * 512]); \
  }

#define PHASE(MH, NH, STAGECODE, TAILWAIT)                                   \
  {                                                                          \
    bf16x8 af[4][2], bfr[2][2];                                              \
    _Pragma("unroll") for (int ii = 0; ii < 4; ++ii)                         \
        _Pragma("unroll") for (int ks = 0; ks < 2; ++ks)                     \
            af[ii][ks] = *(const bf16x8*)&smem[ab +                          \
                (waveM * 8 + (MH) * 4 + ii) * 1024 + ks * 512 + rdOff];      \
    _Pragma("unroll") for (int jj = 0; jj < 2; ++jj)                         \
        _Pragma("unroll") for (int ks = 0; ks < 2; ++ks)                     \
            bfr[jj][ks] = *(const bf16x8*)&smem[bb +                         \
                (waveN * 4 + (NH) * 2 + jj) * 1024 + ks * 512 + rdOff];      \
    STAGECODE;                                                               \
    asm volatile("" ::: "memory");                                           \
    __builtin_amdgcn_s_barrier();                                            \
    asm volatile("" ::: "memory");                                           \
    __builtin_amdgcn_s_setprio(1);                                           \
    _Pragma("unroll") for (int ii = 0; ii < 4; ++ii)                         \
        _Pragma("unroll") for (int jj = 0; jj < 2; ++jj)                     \
            _Pragma("unroll") for (int ks = 0; ks < 2; ++ks)                 \
                acc[(MH) * 4 + ii][(NH) * 2 + jj] =                          \
                    __builtin_amdgcn_mfma_f32_16x16x32_bf16(                 \
                        af[ii][ks], bfr[jj][ks],                             \
                        acc[(MH) * 4 + ii][(NH) * 2 + jj], 0, 0, 0);         \
    __builtin_amdgcn_s_setprio(0);                                           \
    TAILWAIT;                                                                \
    asm volatile("" ::: "memory");                                           \
    __builtin_amdgcn_s_barrier();                                            \
    asm volatile("" ::: "memory");                                           \
  }

  // prologue: stage tile 0 into buf0, full drain once.
  STAGE_OP(AgS, 0, 0);
  STAGE_OP(BgS, 16384, 0);
  asm volatile("s_waitcnt vmcnt(0)" ::: "memory");
  __builtin_amdgcn_s_barrier();
  asm volatile("" ::: "memory");

  for (int tt = 0; tt < NT; ++tt) {
    const int ab = (tt & 1) * 32768;         // current buf A base (u16)
    const int bb = ab + 16384;               // current buf B base
    const int sab = ((tt + 1) & 1) * 32768;  // next-stage buf bases
    const int sbb = sab + 16384;
    const int kN = (tt + 1) * 64;
    const bool st = (tt + 1) < NT;
    PHASE(0, 0, if (st) STAGE_OP(AgS, sab, kN), )
    PHASE(0, 1, if (st) STAGE_OP(BgS, sbb, kN), )
    PHASE(1, 0, , )
    PHASE(1, 1, , asm volatile("s_waitcnt vmcnt(0)" ::: "memory"))
  }
#undef PHASE
#undef STAGE_OP

  __syncthreads();  // LDS reusable for epilogue repack

  float biasf[4];
#pragma unroll
  for (int j = 0; j < 4; ++j)
    biasf[j] = b2f(bias[bn + waveN * 64 + j * 16 + l15]);

  // C/D frag: col = lane&15, row = (lane>>4)*4 + reg  [m89/m91]
  if (out_f32_if_flag && f) {
    float* C = (float*)Cout;
#pragma unroll
    for (int i = 0; i < 8; ++i) {
      const int row0 = waveM * 128 + i * 16 + (lane >> 4) * 4;
#pragma unroll
      for (int j = 0; j < 4; ++j) {
        const int col = waveN * 64 + j * 16 + l15;
#pragma unroll
        for (int r = 0; r < 4; ++r)
          C[(size_t)(bm + row0 + r) * N + bn + col] = acc[i][j][r] + biasf[j];
      }
    }
  } else {
    // bf16 out: repack 128 rows at a time through LDS (64 KB = 128x256 u16)
    u16* C = (u16*)Cout;
#pragma unroll
    for (int h = 0; h < 2; ++h) {
      if (waveM == h) {
#pragma unroll
        for (int i = 0; i < 8; ++i) {
          const int row0 = i * 16 + (lane >> 4) * 4;  // 0..127
#pragma unroll
          for (int j = 0; j < 4; ++j) {
            const int col = waveN * 64 + j * 16 + l15;
#pragma unroll
            for (int r = 0; r < 4; ++r)
              smem[(row0 + r) * 256 + col] = f2b(acc[i][j][r] + biasf[j]);
          }
        }
      }
      __syncthreads();
#pragma unroll
      for (int s = 0; s < 8; ++s) {
        const int vi = s * 512 + t;
        const int row = vi >> 5;           // 0..127
        const int col = (vi & 31) * 8;     // 0..248
        u16x8 v = *(const u16x8*)&smem[row * 256 + col];
        *(u16x8*)&C[(size_t)(bm + h * 128 + row) * N + bn + col] = v;
      }
      __syncthreads();
    }
  }
}

// ------------------------------------------------------------- attention
// qkv[rows][1536]: Q [0,512), K [512,1024), V [1024,1536); head h at h*64.
// One wave per WINDOW. lane = h*8 + dg: head h = lane>>3, d-elems
// dg*8..dg*8+7. Dot over d=64 = 8 local FMA + 3-level butterfly within the
// 8-lane d-group. All loads/stores u16x8 (16 B/lane, coalesced 1 KB rows).
__global__ __launch_bounds__(256) void attn_win(const u16* __restrict__ qkv,
                                                u16* __restrict__ o,
                                                int nwin) {
  const int w = blockIdx.x * 4 + (threadIdx.x >> 6);
  if (w >= nwin) return;
  const int lane = threadIdx.x & 63;
  const int h = lane >> 3;        // head 0..7
  const int d0 = (lane & 7) * 8;  // d-group base 0..56
  const u16* base = qkv + (size_t)w * (5 * 1536) + h * 64 + d0;

  float qf[5][8], kf[5][8], vf[5][8];
#pragma unroll
  for (int i = 0; i < 5; ++i) {
    u16x8 vq = *(const u16x8*)&base[i * 1536];
    u16x8 vk = *(const u16x8*)&base[i * 1536 + 512];
    u16x8 vv = *(const u16x8*)&base[i * 1536 + 1024];
#pragma unroll
    for (int e = 0; e < 8; ++e) {
      qf[i][e] = b2f(vq[e]);
      kf[i][e] = b2f(vk[e]);
      vf[i][e] = b2f(vv[e]);
    }
  }

  // partial scores over this lane's 8 d-elems
  float s[5][5];
#pragma unroll
  for (int i = 0; i < 5; ++i)
#pragma unroll
    for (int j = 0; j < 5; ++j) {
      float acc = 0.f;
#pragma unroll
      for (int e = 0; e < 8; ++e) acc += qf[i][e] * kf[j][e];
      s[i][j] = acc;
    }
  // butterfly within 8-lane d-group (lane bits 0-2): full dot over d=64
#pragma unroll
  for (int off = 1; off < 8; off <<= 1) {
#pragma unroll
    for (int i = 0; i < 5; ++i)
#pragma unroll
      for (int j = 0; j < 5; ++j) s[i][j] += __shfl_xor(s[i][j], off, 64);
  }

  const float SCALE = 0.125f;  // 64^-0.5
  u16* ob = o + (size_t)w * (5 * 512) + h * 64 + d0;
#pragma unroll
  for (int i = 0; i < 5; ++i) {
    float m = s[i][0];
#pragma unroll
    for (int j = 1; j < 5; ++j) m = fmaxf(m, s[i][j]);
    float e0[5], l = 0.f;
#pragma unroll
    for (int j = 0; j < 5; ++j) {
      e0[j] = __expf((s[i][j] - m) * SCALE);
      l += e0[j];
    }
    const float rl = 1.f / l;
    u16x8 out;
#pragma unroll
    for (int e = 0; e < 8; ++e) {
      float acc = 0.f;
#pragma unroll
      for (int j = 0; j < 5; ++j) acc += e0[j] * vf[j][e];
      out[e] = f2b(acc * rl);
    }
    *(u16x8*)&ob[i * 512] = out;
  }
}

// ---------------------------------------------------------------- launch
extern "C" void kernel_launch(void* const* d_in, const int* in_sizes, int n_in,
                              void* d_out, int out_size, void* d_ws,
                              size_t ws_size, hipStream_t stream) {
  const void* x      = d_in[0];  // [102400][512]  fp32 or bf16
  const void* qkv_w  = d_in[1];  // [512][1536]
  const void* qkv_b  = d_in[2];  // [1536]
  const void* proj_w = d_in[3];  // [512][512]
  const void* proj_b = d_in[4];  // [512]

  const int M = 102400, K = 512, N1 = 1536, N2 = 512;

  // Dynamic chunking: CH=1 needs ~527 MB of ws; fall back if less.
  const size_t fixed = 8192 + 1572864 + 524288 + (size_t)M * 512 * 2;
  int CH = 4;
  if (ws_size >= fixed + (size_t)M * 2048 * 2) CH = 1;
  else if (ws_size >= fixed + (size_t)(M / 2) * 2048 * 2) CH = 2;
  const int MC = M / CH;

  char* ws = (char*)d_ws;
  uint32_t* flag = (uint32_t*)ws;                       // @0
  u16* bq      = (u16*)(ws + 256);                      // 1536*2
  u16* bp      = (u16*)(ws + 256 + 3072);               // 512*2
  u16* wt_qkv  = (u16*)(ws + 8192);                     // 1536*512*2
  u16* wt_proj = (u16*)(ws + 8192 + 1572864);           // 512*512*2
  u16* attnb   = (u16*)(ws + 8192 + 1572864 + 524288);  // M*512*2 = 104.9 MB
  u16* qkvc    = (u16*)((char*)attnb + (size_t)M * 512 * 2);   // MC*1536*2
  u16* xbc     = (u16*)((char*)qkvc + (size_t)MC * 1536 * 2);  // MC*512*2

  k_sniff_bias<<<1, 1024, 0, stream>>>((const uint32_t*)x, qkv_b, proj_b, flag,
                                       bq, bp);
  k_prep_w2<<<dim3(64, 16), dim3(32, 8), 0, stream>>>(qkv_w, proj_w, wt_qkv,
                                                      wt_proj, flag);
  for (int c = 0; c < CH; ++c) {
    const size_t roff = (size_t)c * MC * 512;
    k_conv_x<<<MC * 512 / 2048, 256, 0, stream>>>((const float*)x + roff, xbc,
                                                  flag, MC * 512);
    // qkv grid: (1536/256) x (MC/256); CH=1 -> 6x400=2400 blocks (%8==0)
    gemm_bt_bias<<<dim3(N1 / BN, MC / BM), 512, 0, stream>>>(
        (const u16*)x + roff, xbc, wt_qkv, bq, qkvc, flag, N1, K, 0);
    // one wave per window: MC/5 windows, 4 waves/block
    attn_win<<<(MC / 5) / 4, 256, 0, stream>>>(qkvc, (u16*)attnb + roff,
                                               MC / 5);
  }
  // proj grid 2 x 400 = 800 blocks (%8==0)
  gemm_bt_bias<<<dim3(N2 / BN, M / BM), 512, 0, stream>>>(
      attnb, attnb, wt_proj, bp, d_out, flag, N2, K, 1);
}